// Round 2
// baseline (2467.735 us; speedup 1.0000x reference)
//
#include <hip/hip_runtime.h>
#include <hip/hip_bf16.h>

#define N_NODES 100000
#define N_EDGES 1600000
#define NODE_DIM 128
#define MEM 64
#define NEG_SLOPE 0.2f
#define NB ((N_NODES + 255) / 256)  // 391 scan blocks

__device__ __forceinline__ float lrelu(float v) { return v >= 0.f ? v : NEG_SLOPE * v; }

// Kernel A: per node -- projected = state@w_in.T + b_in; mem_enh = proj+goal+mem;
// xt = mem_enh@w_gat.T; a_s = xt.att_src; a_d = xt.att_dst
// 1024 threads (16 waves, node per wave), 62.4KB LDS -> 2 blocks/CU.
__global__ __launch_bounds__(1024) void kA(
    const float* __restrict__ state, const float* __restrict__ goal,
    const float* __restrict__ mem, const float* __restrict__ w_in,
    const float* __restrict__ b_in, const float* __restrict__ w_gat,
    const float* __restrict__ att_src, const float* __restrict__ att_dst,
    float* __restrict__ me_out, float* __restrict__ xt_out,
    float* __restrict__ as_out, float* __restrict__ ad_out)
{
    __shared__ float s_win[64 * 130];   // pad 130: even stride, 2-way bank alias (free)
    __shared__ float s_wgat[64 * 66];
    __shared__ float s_state[16][128];
    __shared__ float s_me[16][64];
    const int tid = threadIdx.x;
    for (int i = tid; i < 64 * 128; i += 1024) s_win[(i >> 7) * 130 + (i & 127)] = w_in[i];
    for (int i = tid; i < 64 * 64; i += 1024) s_wgat[(i >> 6) * 66 + (i & 63)] = w_gat[i];
    __syncthreads();
    const int wave = tid >> 6, lane = tid & 63;
    const float bin = b_in[lane];
    const float asrc = att_src[lane], adst = att_dst[lane];
    const int npad = (N_NODES + 15) & ~15;
    for (int base = blockIdx.x * 16; base < npad; base += gridDim.x * 16) {
        const int node = base + wave;
        const bool act = node < N_NODES;
        if (act) {
            const float* sp = state + (long)node * NODE_DIM;
            s_state[wave][lane] = sp[lane];
            s_state[wave][lane + 64] = sp[lane + 64];
        }
        __syncthreads();
        float me = 0.f;
        if (act) {
            float acc = bin;
            const float2* wr = (const float2*)(s_win + lane * 130);
            const float2* sv = (const float2*)(s_state[wave]);
            #pragma unroll
            for (int k = 0; k < 64; ++k) {
                float2 w2 = wr[k], s2 = sv[k];
                acc += w2.x * s2.x + w2.y * s2.y;
            }
            const long off = (long)node * MEM + lane;
            me = acc + goal[off] + mem[off];
            s_me[wave][lane] = me;
        }
        __syncthreads();
        if (act) {
            float acc = 0.f;
            const float2* wr = (const float2*)(s_wgat + lane * 66);
            const float2* sv = (const float2*)(s_me[wave]);
            #pragma unroll
            for (int k = 0; k < 32; ++k) {
                float2 w2 = wr[k], s2 = sv[k];
                acc += w2.x * s2.x + w2.y * s2.y;
            }
            const long off = (long)node * MEM + lane;
            xt_out[off] = acc;
            me_out[off] = me;
            float ps = acc * asrc, pd = acc * adst;
            #pragma unroll
            for (int o = 32; o; o >>= 1) {
                ps += __shfl_xor(ps, o);
                pd += __shfl_xor(pd, o);
            }
            if (lane == 0) { as_out[node] = ps; ad_out[node] = pd; }
        }
        __syncthreads();
    }
}

// Kernel H: in-degree histogram (int atomics)
__global__ __launch_bounds__(256) void kH(const int* __restrict__ dst, int* __restrict__ deg) {
    const int e = blockIdx.x * 256 + threadIdx.x;
    if (e < N_EDGES) atomicAdd(deg + dst[e], 1);
}

// Scan kernel 1: per-256-block sums of deg
__global__ __launch_bounds__(256) void kS1(const int* __restrict__ deg, int* __restrict__ bsums) {
    const int i = blockIdx.x * 256 + threadIdx.x;
    int s = (i < N_NODES) ? deg[i] : 0;
    #pragma unroll
    for (int o = 32; o; o >>= 1) s += __shfl_xor(s, o);
    __shared__ int ws_[4];
    if ((threadIdx.x & 63) == 0) ws_[threadIdx.x >> 6] = s;
    __syncthreads();
    if (threadIdx.x == 0) bsums[blockIdx.x] = ws_[0] + ws_[1] + ws_[2] + ws_[3];
}

// Scan kernel 2: exclusive scan of NB block sums (single block)
__global__ __launch_bounds__(512) void kS2(int* __restrict__ bsums) {
    const int t = threadIdx.x;
    int v = (t < NB) ? bsums[t] : 0;
    int x = v;
    #pragma unroll
    for (int o = 1; o < 64; o <<= 1) {
        int y = __shfl_up(x, o);
        if ((t & 63) >= o) x += y;
    }
    __shared__ int wt[8];
    if ((t & 63) == 63) wt[t >> 6] = x;
    __syncthreads();
    int woff = 0;
    for (int w = 0; w < (t >> 6); ++w) woff += wt[w];
    if (t < NB) bsums[t] = woff + x - v;  // exclusive
}

// Scan kernel 3: per-block exclusive scan + block offset -> row_ptr, cursor
__global__ __launch_bounds__(256) void kS3(const int* __restrict__ deg, const int* __restrict__ bsums,
                                           int* __restrict__ row_ptr, int* __restrict__ cursor) {
    const int i = blockIdx.x * 256 + threadIdx.x;
    const int t = threadIdx.x;
    int v = (i < N_NODES) ? deg[i] : 0;
    int x = v;
    #pragma unroll
    for (int o = 1; o < 64; o <<= 1) {
        int y = __shfl_up(x, o);
        if ((t & 63) >= o) x += y;
    }
    __shared__ int wt[4];
    if ((t & 63) == 63) wt[t >> 6] = x;
    __syncthreads();
    int woff = bsums[blockIdx.x];
    for (int w = 0; w < (t >> 6); ++w) woff += wt[w];
    const int excl = woff + x - v;
    if (i < N_NODES) {
        row_ptr[i] = excl;
        cursor[i] = excl;
        if (i == N_NODES - 1) row_ptr[N_NODES] = excl + v;
    }
}

// Kernel P: place edges into CSR slots; precompute leaky logit e
__global__ __launch_bounds__(256) void kP(
    const int* __restrict__ src, const int* __restrict__ dst,
    const float* __restrict__ as_, const float* __restrict__ ad_,
    int* __restrict__ cursor, int2* __restrict__ csr)
{
    const int e = blockIdx.x * 256 + threadIdx.x;
    if (e >= N_EDGES) return;
    const int s = src[e], d = dst[e];
    const int slot = atomicAdd(cursor + d, 1);
    const float ev = lrelu(as_[s] + ad_[d]);
    csr[slot] = make_int2(s, __float_as_int(ev));
}

// Kernel G: wave per node -- max, softmax, weighted gather of xt rows,
// x = mem_enh + ctx + b_gat written in place over me_buf. Self-loop included.
__global__ __launch_bounds__(256) void kG(
    const int* __restrict__ row_ptr, const int2* __restrict__ csr,
    const float* __restrict__ as_, const float* __restrict__ ad_,
    const float* __restrict__ xt, const float* __restrict__ b_gat,
    float* __restrict__ me /* in: mem_enh, out: x */)
{
    const int wave = threadIdx.x >> 6, lane = threadIdx.x & 63;
    const float bg = b_gat[lane];
    for (int node = blockIdx.x * 4 + wave; node < N_NODES; node += gridDim.x * 4) {
        const int beg = row_ptr[node], end = row_ptr[node + 1];
        const float e_self = lrelu(as_[node] + ad_[node]);
        // phase 1: max over incoming edges + self loop (lane-parallel)
        float m = e_self;
        for (int j = beg + lane; j < end; j += 64)
            m = fmaxf(m, __int_as_float(csr[j].y));
        #pragma unroll
        for (int o = 32; o; o >>= 1) m = fmaxf(m, __shfl_xor(m, o));
        // phase 2: accumulate numerators (per-lane dim) + denom
        float acc = 0.f, den = 0.f;
        for (int j = beg; j < end; ++j) {
            const int2 c = csr[j];
            const float w = __expf(__int_as_float(c.y) - m);
            den += w;
            acc += xt[(long)c.x * MEM + lane] * w;
        }
        const float wself = __expf(e_self - m);
        den += wself;
        acc += xt[(long)node * MEM + lane] * wself;
        const long off = (long)node * MEM + lane;
        me[off] = me[off] + acc / den + bg;
    }
}

// Kernel E: GRU cell. x precomputed by kG. 1024 threads, 109.6KB LDS -> 4 waves/SIMD.
__global__ __launch_bounds__(1024) void kE(
    const float* __restrict__ x, const float* __restrict__ h,
    const float* __restrict__ w_ih, const float* __restrict__ w_hh,
    const float* __restrict__ b_ih, const float* __restrict__ b_hh,
    float* __restrict__ out)
{
    __shared__ float s_wih[192 * 66];
    __shared__ float s_whh[192 * 66];
    __shared__ float s_x[16][64];
    __shared__ float s_h[16][64];
    const int tid = threadIdx.x;
    for (int i = tid; i < 192 * 64; i += 1024) {
        const int r = i >> 6, c = i & 63;
        s_wih[r * 66 + c] = w_ih[i];
        s_whh[r * 66 + c] = w_hh[i];
    }
    __syncthreads();
    const int wave = tid >> 6, lane = tid & 63;
    const float bir = b_ih[lane], biz = b_ih[64 + lane], bin = b_ih[128 + lane];
    const float bhr = b_hh[lane], bhz = b_hh[64 + lane], bhn = b_hh[128 + lane];
    const int npad = (N_NODES + 15) & ~15;
    for (int base = blockIdx.x * 16; base < npad; base += gridDim.x * 16) {
        const int node = base + wave;
        const bool act = node < N_NODES;
        float hval = 0.f;
        if (act) {
            const long off = (long)node * MEM + lane;
            s_x[wave][lane] = x[off];
            hval = h[off];
            s_h[wave][lane] = hval;
        }
        __syncthreads();
        if (act) {
            float ir = bir, iz = biz, inn = bin, hr = bhr, hz = bhz, hn = bhn;
            const float2* wi0 = (const float2*)(s_wih + lane * 66);
            const float2* wi1 = (const float2*)(s_wih + (64 + lane) * 66);
            const float2* wi2 = (const float2*)(s_wih + (128 + lane) * 66);
            const float2* wh0 = (const float2*)(s_whh + lane * 66);
            const float2* wh1 = (const float2*)(s_whh + (64 + lane) * 66);
            const float2* wh2 = (const float2*)(s_whh + (128 + lane) * 66);
            const float2* sx = (const float2*)(s_x[wave]);
            const float2* sh = (const float2*)(s_h[wave]);
            #pragma unroll
            for (int k = 0; k < 32; ++k) {
                const float2 xv = sx[k], hv = sh[k];
                float2 a;
                a = wi0[k]; ir  += xv.x * a.x + xv.y * a.y;
                a = wi1[k]; iz  += xv.x * a.x + xv.y * a.y;
                a = wi2[k]; inn += xv.x * a.x + xv.y * a.y;
                a = wh0[k]; hr  += hv.x * a.x + hv.y * a.y;
                a = wh1[k]; hz  += hv.x * a.x + hv.y * a.y;
                a = wh2[k]; hn  += hv.x * a.x + hv.y * a.y;
            }
            const float r = 1.f / (1.f + __expf(-(ir + hr)));
            const float z = 1.f / (1.f + __expf(-(iz + hz)));
            const float n = tanhf(inn + r * hn);
            out[(long)node * MEM + lane] = (1.f - z) * n + z * hval;
        }
        __syncthreads();
    }
}

extern "C" void kernel_launch(void* const* d_in, const int* in_sizes, int n_in,
                              void* d_out, int out_size, void* d_ws, size_t ws_size,
                              hipStream_t stream) {
    const float* state = (const float*)d_in[0];
    const float* goal  = (const float*)d_in[1];
    const float* mem   = (const float*)d_in[2];
    const int*   ei    = (const int*)d_in[3];
    const float* w_in  = (const float*)d_in[4];
    const float* b_in  = (const float*)d_in[5];
    const float* w_gat = (const float*)d_in[6];
    const float* att_s = (const float*)d_in[7];
    const float* att_d = (const float*)d_in[8];
    const float* b_gat = (const float*)d_in[9];
    const float* w_ih  = (const float*)d_in[10];
    const float* w_hh  = (const float*)d_in[11];
    const float* b_ih  = (const float*)d_in[12];
    const float* b_hh  = (const float*)d_in[13];
    float* out = (float*)d_out;

    const int* e_src = ei;
    const int* e_dst = ei + N_EDGES;

    // workspace layout (4-byte elements)
    float* ws = (float*)d_ws;
    float* me_buf  = ws;                              // N*64 (becomes x after kG)
    float* xt_buf  = me_buf + (long)N_NODES * MEM;    // N*64
    float* as_buf  = xt_buf + (long)N_NODES * MEM;    // N
    float* ad_buf  = as_buf + N_NODES;                // N
    int*   deg     = (int*)(ad_buf + N_NODES);        // N
    int*   row_ptr = deg + N_NODES;                   // N+1
    int*   cursor  = row_ptr + N_NODES + 1;           // N
    int*   bsums   = cursor + N_NODES;                // NB
    long csr_off = (long)(bsums + NB - (int*)d_ws);
    csr_off = (csr_off + 1) & ~1L;                    // 8B align
    int2*  csr     = (int2*)((int*)d_ws + csr_off);   // E int2

    hipMemsetAsync(deg, 0, N_NODES * sizeof(int), stream);

    hipLaunchKernelGGL(kA, dim3(512), dim3(1024), 0, stream,
        state, goal, mem, w_in, b_in, w_gat, att_s, att_d,
        me_buf, xt_buf, as_buf, ad_buf);

    hipLaunchKernelGGL(kH, dim3((N_EDGES + 255) / 256), dim3(256), 0, stream, e_dst, deg);
    hipLaunchKernelGGL(kS1, dim3(NB), dim3(256), 0, stream, deg, bsums);
    hipLaunchKernelGGL(kS2, dim3(1), dim3(512), 0, stream, bsums);
    hipLaunchKernelGGL(kS3, dim3(NB), dim3(256), 0, stream, deg, bsums, row_ptr, cursor);
    hipLaunchKernelGGL(kP, dim3((N_EDGES + 255) / 256), dim3(256), 0, stream,
        e_src, e_dst, as_buf, ad_buf, cursor, csr);

    hipLaunchKernelGGL(kG, dim3(2048), dim3(256), 0, stream,
        row_ptr, csr, as_buf, ad_buf, xt_buf, b_gat, me_buf);

    hipLaunchKernelGGL(kE, dim3(256), dim3(1024), 0, stream,
        me_buf, mem, w_ih, w_hh, b_ih, b_hh, out);
}

// Round 3
// 773.607 us; speedup vs baseline: 3.1899x; 3.1899x over previous
//
#include <hip/hip_runtime.h>
#include <hip/hip_bf16.h>

#define N_NODES 100000
#define N_EDGES 1600000
#define NODE_DIM 128
#define MEM 64
#define NEG_SLOPE 0.2f
#define NB ((N_NODES + 255) / 256)  // 391 scan blocks
#define GRP 8                       // nodes per kE group

__device__ __forceinline__ float lrelu(float v) { return v >= 0.f ? v : NEG_SLOPE * v; }

// Kernel A: per node -- projected = state@w_in.T + b_in; mem_enh = proj+goal+mem;
// xt = mem_enh@w_gat.T; a_s = xt.att_src; a_d = xt.att_dst
__global__ __launch_bounds__(1024) void kA(
    const float* __restrict__ state, const float* __restrict__ goal,
    const float* __restrict__ mem, const float* __restrict__ w_in,
    const float* __restrict__ b_in, const float* __restrict__ w_gat,
    const float* __restrict__ att_src, const float* __restrict__ att_dst,
    float* __restrict__ me_out, float* __restrict__ xt_out,
    float* __restrict__ as_out, float* __restrict__ ad_out)
{
    __shared__ float s_win[64 * 130];   // pad 130: even stride, 2-way bank alias (free)
    __shared__ float s_wgat[64 * 66];
    __shared__ float s_state[16][128];
    __shared__ float s_me[16][64];
    const int tid = threadIdx.x;
    for (int i = tid; i < 64 * 128; i += 1024) s_win[(i >> 7) * 130 + (i & 127)] = w_in[i];
    for (int i = tid; i < 64 * 64; i += 1024) s_wgat[(i >> 6) * 66 + (i & 63)] = w_gat[i];
    __syncthreads();
    const int wave = tid >> 6, lane = tid & 63;
    const float bin = b_in[lane];
    const float asrc = att_src[lane], adst = att_dst[lane];
    const int npad = (N_NODES + 15) & ~15;
    for (int base = blockIdx.x * 16; base < npad; base += gridDim.x * 16) {
        const int node = base + wave;
        const bool act = node < N_NODES;
        if (act) {
            const float* sp = state + (long)node * NODE_DIM;
            s_state[wave][lane] = sp[lane];
            s_state[wave][lane + 64] = sp[lane + 64];
        }
        __syncthreads();
        float me = 0.f;
        if (act) {
            float acc = bin;
            const float2* wr = (const float2*)(s_win + lane * 130);
            const float2* sv = (const float2*)(s_state[wave]);
            #pragma unroll
            for (int k = 0; k < 64; ++k) {
                float2 w2 = wr[k], s2 = sv[k];
                acc += w2.x * s2.x + w2.y * s2.y;
            }
            const long off = (long)node * MEM + lane;
            me = acc + goal[off] + mem[off];
            s_me[wave][lane] = me;
        }
        __syncthreads();
        if (act) {
            float acc = 0.f;
            const float2* wr = (const float2*)(s_wgat + lane * 66);
            const float2* sv = (const float2*)(s_me[wave]);
            #pragma unroll
            for (int k = 0; k < 32; ++k) {
                float2 w2 = wr[k], s2 = sv[k];
                acc += w2.x * s2.x + w2.y * s2.y;
            }
            const long off = (long)node * MEM + lane;
            xt_out[off] = acc;
            me_out[off] = me;
            float ps = acc * asrc, pd = acc * adst;
            #pragma unroll
            for (int o = 32; o; o >>= 1) {
                ps += __shfl_xor(ps, o);
                pd += __shfl_xor(pd, o);
            }
            if (lane == 0) { as_out[node] = ps; ad_out[node] = pd; }
        }
        __syncthreads();
    }
}

// Kernel H: in-degree histogram (int atomics)
__global__ __launch_bounds__(256) void kH(const int* __restrict__ dst, int* __restrict__ deg) {
    const int e = blockIdx.x * 256 + threadIdx.x;
    if (e < N_EDGES) atomicAdd(deg + dst[e], 1);
}

// Scan kernel 1: per-256-block sums of deg
__global__ __launch_bounds__(256) void kS1(const int* __restrict__ deg, int* __restrict__ bsums) {
    const int i = blockIdx.x * 256 + threadIdx.x;
    int s = (i < N_NODES) ? deg[i] : 0;
    #pragma unroll
    for (int o = 32; o; o >>= 1) s += __shfl_xor(s, o);
    __shared__ int ws_[4];
    if ((threadIdx.x & 63) == 0) ws_[threadIdx.x >> 6] = s;
    __syncthreads();
    if (threadIdx.x == 0) bsums[blockIdx.x] = ws_[0] + ws_[1] + ws_[2] + ws_[3];
}

// Scan kernel 2: exclusive scan of NB block sums (single block)
__global__ __launch_bounds__(512) void kS2(int* __restrict__ bsums) {
    const int t = threadIdx.x;
    int v = (t < NB) ? bsums[t] : 0;
    int x = v;
    #pragma unroll
    for (int o = 1; o < 64; o <<= 1) {
        int y = __shfl_up(x, o);
        if ((t & 63) >= o) x += y;
    }
    __shared__ int wt[8];
    if ((t & 63) == 63) wt[t >> 6] = x;
    __syncthreads();
    int woff = 0;
    for (int w = 0; w < (t >> 6); ++w) woff += wt[w];
    if (t < NB) bsums[t] = woff + x - v;  // exclusive
}

// Scan kernel 3: per-block exclusive scan + block offset -> row_ptr, cursor
__global__ __launch_bounds__(256) void kS3(const int* __restrict__ deg, const int* __restrict__ bsums,
                                           int* __restrict__ row_ptr, int* __restrict__ cursor) {
    const int i = blockIdx.x * 256 + threadIdx.x;
    const int t = threadIdx.x;
    int v = (i < N_NODES) ? deg[i] : 0;
    int x = v;
    #pragma unroll
    for (int o = 1; o < 64; o <<= 1) {
        int y = __shfl_up(x, o);
        if ((t & 63) >= o) x += y;
    }
    __shared__ int wt[4];
    if ((t & 63) == 63) wt[t >> 6] = x;
    __syncthreads();
    int woff = bsums[blockIdx.x];
    for (int w = 0; w < (t >> 6); ++w) woff += wt[w];
    const int excl = woff + x - v;
    if (i < N_NODES) {
        row_ptr[i] = excl;
        cursor[i] = excl;
        if (i == N_NODES - 1) row_ptr[N_NODES] = excl + v;
    }
}

// Kernel P: place edges into CSR slots; precompute leaky logit e
__global__ __launch_bounds__(256) void kP(
    const int* __restrict__ src, const int* __restrict__ dst,
    const float* __restrict__ as_, const float* __restrict__ ad_,
    int* __restrict__ cursor, int2* __restrict__ csr)
{
    const int e = blockIdx.x * 256 + threadIdx.x;
    if (e >= N_EDGES) return;
    const int s = src[e], d = dst[e];
    const int slot = atomicAdd(cursor + d, 1);
    const float ev = lrelu(as_[s] + ad_[d]);
    csr[slot] = make_int2(s, __float_as_int(ev));
}

// Kernel G: wave per node -- max, softmax, weighted gather of xt rows,
// x = mem_enh + ctx + b_gat written in place over me_buf. Self-loop included.
__global__ __launch_bounds__(256) void kG(
    const int* __restrict__ row_ptr, const int2* __restrict__ csr,
    const float* __restrict__ as_, const float* __restrict__ ad_,
    const float* __restrict__ xt, const float* __restrict__ b_gat,
    float* __restrict__ me /* in: mem_enh, out: x */)
{
    const int wave = threadIdx.x >> 6, lane = threadIdx.x & 63;
    const float bg = b_gat[lane];
    for (int node = blockIdx.x * 4 + wave; node < N_NODES; node += gridDim.x * 4) {
        const int beg = row_ptr[node], end = row_ptr[node + 1];
        const float e_self = lrelu(as_[node] + ad_[node]);
        float m = e_self;
        for (int j = beg + lane; j < end; j += 64)
            m = fmaxf(m, __int_as_float(csr[j].y));
        #pragma unroll
        for (int o = 32; o; o >>= 1) m = fmaxf(m, __shfl_xor(m, o));
        float acc = 0.f, den = 0.f;
        for (int j = beg; j < end; ++j) {
            const int2 c = csr[j];
            const float w = __expf(__int_as_float(c.y) - m);
            den += w;
            acc += xt[(long)c.x * MEM + lane] * w;
        }
        const float wself = __expf(e_self - m);
        den += wself;
        acc += xt[(long)node * MEM + lane] * wself;
        const long off = (long)node * MEM + lane;
        me[off] = me[off] + acc / den + bg;
    }
}

// Kernel E v3: column-parallel GRU, 8-node blocking, bf16-packed weights in LDS.
// 384 threads: thread jj owns gate-column jj (jj<192: gi via x@W_ih.T; else gh via h@W_hh.T).
// LDS exactly 64KB -> 2 blocks/CU. ~30 VGPR, no spill.
__global__ __launch_bounds__(384) void kE(
    const float* __restrict__ x, const float* __restrict__ h,
    const float* __restrict__ w_ih, const float* __restrict__ w_hh,
    const float* __restrict__ b_ih, const float* __restrict__ b_hh,
    float* __restrict__ out)
{
    __shared__ unsigned s_wt[32 * 384];            // [k-pair p][jj] : packed bf16 {W[jj][2p], W[jj][2p+1]}
    __shared__ __align__(16) float s_xh[32][2][16]; // [p][x|h][(k&1)*8 + node]
    __shared__ float s_gates[GRP][384];
    const int tid = threadIdx.x;                   // = jj
    // stage weights, packed bf16 (RNE) -- once per block
    {
        const float* W = (tid < 192) ? (w_ih + tid * 64) : (w_hh + (long)(tid - 192) * 64);
        for (int p = 0; p < 32; ++p) {
            unsigned u0 = __float_as_uint(W[2 * p]);
            unsigned u1 = __float_as_uint(W[2 * p + 1]);
            u0 = (u0 + 0x7FFFu + ((u0 >> 16) & 1u)) >> 16;
            u1 = (u1 + 0x7FFFu + ((u1 >> 16) & 1u)) >> 16;
            s_wt[p * 384 + tid] = u0 | (u1 << 16);
        }
    }
    const float bias = (tid < 192) ? b_ih[tid] : b_hh[tid - 192];
    const int sel = (tid < 192) ? 0 : 1;           // wave-uniform (192 = 3 waves)
    const int ngroups = N_NODES / GRP;             // 12500 exactly
    for (int g = blockIdx.x; g < ngroups; g += gridDim.x) {
        const int n0 = g * GRP;
        __syncthreads();   // covers weight staging (1st iter) + s_xh/s_gates reuse
        for (int i = tid; i < GRP * 64; i += 384) {
            const int n = i >> 6, k = i & 63;
            const long off = (long)(n0 + n) * MEM + k;
            s_xh[k >> 1][0][(k & 1) * 8 + n] = x[off];
            s_xh[k >> 1][1][(k & 1) * 8 + n] = h[off];
        }
        __syncthreads();
        float acc[GRP];
        #pragma unroll
        for (int n = 0; n < GRP; ++n) acc[n] = bias;
        #pragma unroll 4
        for (int p = 0; p < 32; ++p) {
            const unsigned u = s_wt[p * 384 + tid];
            const float w0 = __uint_as_float(u << 16);          // W[jj][2p]
            const float w1 = __uint_as_float(u & 0xFFFF0000u);  // W[jj][2p+1]
            const float4 v0 = *(const float4*)&s_xh[p][sel][0];  // nodes 0-3 @ k=2p
            const float4 v1 = *(const float4*)&s_xh[p][sel][4];  // nodes 4-7 @ k=2p
            const float4 v2 = *(const float4*)&s_xh[p][sel][8];  // nodes 0-3 @ k=2p+1
            const float4 v3 = *(const float4*)&s_xh[p][sel][12]; // nodes 4-7 @ k=2p+1
            acc[0] += w0 * v0.x + w1 * v2.x;
            acc[1] += w0 * v0.y + w1 * v2.y;
            acc[2] += w0 * v0.z + w1 * v2.z;
            acc[3] += w0 * v0.w + w1 * v2.w;
            acc[4] += w0 * v1.x + w1 * v3.x;
            acc[5] += w0 * v1.y + w1 * v3.y;
            acc[6] += w0 * v1.z + w1 * v3.z;
            acc[7] += w0 * v1.w + w1 * v3.w;
        }
        #pragma unroll
        for (int n = 0; n < GRP; ++n) s_gates[n][tid] = acc[n];
        __syncthreads();
        for (int i = tid; i < GRP * 64; i += 384) {
            const int n = i >> 6, j = i & 63;
            const float gir = s_gates[n][j],       giz = s_gates[n][64 + j],  gin = s_gates[n][128 + j];
            const float ghr = s_gates[n][192 + j], ghz = s_gates[n][256 + j], ghn = s_gates[n][320 + j];
            const float r = 1.f / (1.f + __expf(-(gir + ghr)));
            const float z = 1.f / (1.f + __expf(-(giz + ghz)));
            const float nn = tanhf(gin + r * ghn);
            const long off = (long)(n0 + n) * MEM + j;
            out[off] = (1.f - z) * nn + z * h[off];
        }
    }
}

extern "C" void kernel_launch(void* const* d_in, const int* in_sizes, int n_in,
                              void* d_out, int out_size, void* d_ws, size_t ws_size,
                              hipStream_t stream) {
    const float* state = (const float*)d_in[0];
    const float* goal  = (const float*)d_in[1];
    const float* mem   = (const float*)d_in[2];
    const int*   ei    = (const int*)d_in[3];
    const float* w_in  = (const float*)d_in[4];
    const float* b_in  = (const float*)d_in[5];
    const float* w_gat = (const float*)d_in[6];
    const float* att_s = (const float*)d_in[7];
    const float* att_d = (const float*)d_in[8];
    const float* b_gat = (const float*)d_in[9];
    const float* w_ih  = (const float*)d_in[10];
    const float* w_hh  = (const float*)d_in[11];
    const float* b_ih  = (const float*)d_in[12];
    const float* b_hh  = (const float*)d_in[13];
    float* out = (float*)d_out;

    const int* e_src = ei;
    const int* e_dst = ei + N_EDGES;

    float* ws = (float*)d_ws;
    float* me_buf  = ws;                              // N*64 (becomes x after kG)
    float* xt_buf  = me_buf + (long)N_NODES * MEM;    // N*64
    float* as_buf  = xt_buf + (long)N_NODES * MEM;    // N
    float* ad_buf  = as_buf + N_NODES;                // N
    int*   deg     = (int*)(ad_buf + N_NODES);        // N
    int*   row_ptr = deg + N_NODES;                   // N+1
    int*   cursor  = row_ptr + N_NODES + 1;           // N
    int*   bsums   = cursor + N_NODES;                // NB
    long csr_off = (long)(bsums + NB - (int*)d_ws);
    csr_off = (csr_off + 1) & ~1L;                    // 8B align
    int2*  csr     = (int2*)((int*)d_ws + csr_off);   // E int2

    hipMemsetAsync(deg, 0, N_NODES * sizeof(int), stream);

    hipLaunchKernelGGL(kA, dim3(512), dim3(1024), 0, stream,
        state, goal, mem, w_in, b_in, w_gat, att_s, att_d,
        me_buf, xt_buf, as_buf, ad_buf);

    hipLaunchKernelGGL(kH, dim3((N_EDGES + 255) / 256), dim3(256), 0, stream, e_dst, deg);
    hipLaunchKernelGGL(kS1, dim3(NB), dim3(256), 0, stream, deg, bsums);
    hipLaunchKernelGGL(kS2, dim3(1), dim3(512), 0, stream, bsums);
    hipLaunchKernelGGL(kS3, dim3(NB), dim3(256), 0, stream, deg, bsums, row_ptr, cursor);
    hipLaunchKernelGGL(kP, dim3((N_EDGES + 255) / 256), dim3(256), 0, stream,
        e_src, e_dst, as_buf, ad_buf, cursor, csr);

    hipLaunchKernelGGL(kG, dim3(2048), dim3(256), 0, stream,
        row_ptr, csr, as_buf, ad_buf, xt_buf, b_gat, me_buf);

    hipLaunchKernelGGL(kE, dim3(512), dim3(384), 0, stream,
        me_buf, mem, w_ih, w_hh, b_ih, b_hh, out);
}

// Round 5
// 617.453 us; speedup vs baseline: 3.9966x; 1.2529x over previous
//
#include <hip/hip_runtime.h>
#include <hip/hip_bf16.h>

#define N_NODES 100000
#define N_EDGES 1600000
#define NODE_DIM 128
#define MEM 64
#define NEG_SLOPE 0.2f
#define NB ((N_NODES + 255) / 256)  // 391 scan blocks

typedef __attribute__((ext_vector_type(8))) short short8;
typedef __attribute__((ext_vector_type(4))) float f32x4;

__device__ __forceinline__ float lrelu(float v) { return v >= 0.f ? v : NEG_SLOPE * v; }

// f32 -> bf16 (RNE) bit pattern
__device__ __forceinline__ short bfr(float f) {
    unsigned u = __float_as_uint(f);
    u = (u + 0x7FFFu + ((u >> 16) & 1u)) >> 16;
    return (short)u;
}

// Kernel A: per node -- projected = state@w_in.T + b_in; mem_enh = proj+goal+mem;
// xt = mem_enh@w_gat.T; a_s = xt.att_src; a_d = xt.att_dst
__global__ __launch_bounds__(1024) void kA(
    const float* __restrict__ state, const float* __restrict__ goal,
    const float* __restrict__ mem, const float* __restrict__ w_in,
    const float* __restrict__ b_in, const float* __restrict__ w_gat,
    const float* __restrict__ att_src, const float* __restrict__ att_dst,
    float* __restrict__ me_out, float* __restrict__ xt_out,
    float* __restrict__ as_out, float* __restrict__ ad_out)
{
    __shared__ float s_win[64 * 130];   // pad 130: even stride, 2-way bank alias (free)
    __shared__ float s_wgat[64 * 66];
    __shared__ float s_state[16][128];
    __shared__ float s_me[16][64];
    const int tid = threadIdx.x;
    for (int i = tid; i < 64 * 128; i += 1024) s_win[(i >> 7) * 130 + (i & 127)] = w_in[i];
    for (int i = tid; i < 64 * 64; i += 1024) s_wgat[(i >> 6) * 66 + (i & 63)] = w_gat[i];
    __syncthreads();
    const int wave = tid >> 6, lane = tid & 63;
    const float bin = b_in[lane];
    const float asrc = att_src[lane], adst = att_dst[lane];
    const int npad = (N_NODES + 15) & ~15;
    for (int base = blockIdx.x * 16; base < npad; base += gridDim.x * 16) {
        const int node = base + wave;
        const bool act = node < N_NODES;
        if (act) {
            const float* sp = state + (long)node * NODE_DIM;
            s_state[wave][lane] = sp[lane];
            s_state[wave][lane + 64] = sp[lane + 64];
        }
        __syncthreads();
        float me = 0.f;
        if (act) {
            float acc = bin;
            const float2* wr = (const float2*)(s_win + lane * 130);
            const float2* sv = (const float2*)(s_state[wave]);
            #pragma unroll
            for (int k = 0; k < 64; ++k) {
                float2 w2 = wr[k], s2 = sv[k];
                acc += w2.x * s2.x + w2.y * s2.y;
            }
            const long off = (long)node * MEM + lane;
            me = acc + goal[off] + mem[off];
            s_me[wave][lane] = me;
        }
        __syncthreads();
        if (act) {
            float acc = 0.f;
            const float2* wr = (const float2*)(s_wgat + lane * 66);
            const float2* sv = (const float2*)(s_me[wave]);
            #pragma unroll
            for (int k = 0; k < 32; ++k) {
                float2 w2 = wr[k], s2 = sv[k];
                acc += w2.x * s2.x + w2.y * s2.y;
            }
            const long off = (long)node * MEM + lane;
            xt_out[off] = acc;
            me_out[off] = me;
            float ps = acc * asrc, pd = acc * adst;
            #pragma unroll
            for (int o = 32; o; o >>= 1) {
                ps += __shfl_xor(ps, o);
                pd += __shfl_xor(pd, o);
            }
            if (lane == 0) { as_out[node] = ps; ad_out[node] = pd; }
        }
        __syncthreads();
    }
}

// Kernel H: in-degree histogram (int atomics)
__global__ __launch_bounds__(256) void kH(const int* __restrict__ dst, int* __restrict__ deg) {
    const int e = blockIdx.x * 256 + threadIdx.x;
    if (e < N_EDGES) atomicAdd(deg + dst[e], 1);
}

// Scan kernel 1: per-256-block sums of deg
__global__ __launch_bounds__(256) void kS1(const int* __restrict__ deg, int* __restrict__ bsums) {
    const int i = blockIdx.x * 256 + threadIdx.x;
    int s = (i < N_NODES) ? deg[i] : 0;
    #pragma unroll
    for (int o = 32; o; o >>= 1) s += __shfl_xor(s, o);
    __shared__ int ws_[4];
    if ((threadIdx.x & 63) == 0) ws_[threadIdx.x >> 6] = s;
    __syncthreads();
    if (threadIdx.x == 0) bsums[blockIdx.x] = ws_[0] + ws_[1] + ws_[2] + ws_[3];
}

// Scan kernel 2: exclusive scan of NB block sums (single block)
__global__ __launch_bounds__(512) void kS2(int* __restrict__ bsums) {
    const int t = threadIdx.x;
    int v = (t < NB) ? bsums[t] : 0;
    int x = v;
    #pragma unroll
    for (int o = 1; o < 64; o <<= 1) {
        int y = __shfl_up(x, o);
        if ((t & 63) >= o) x += y;
    }
    __shared__ int wt[8];
    if ((t & 63) == 63) wt[t >> 6] = x;
    __syncthreads();
    int woff = 0;
    for (int w = 0; w < (t >> 6); ++w) woff += wt[w];
    if (t < NB) bsums[t] = woff + x - v;  // exclusive
}

// Scan kernel 3: per-block exclusive scan + block offset -> row_ptr, cursor
__global__ __launch_bounds__(256) void kS3(const int* __restrict__ deg, const int* __restrict__ bsums,
                                           int* __restrict__ row_ptr, int* __restrict__ cursor) {
    const int i = blockIdx.x * 256 + threadIdx.x;
    const int t = threadIdx.x;
    int v = (i < N_NODES) ? deg[i] : 0;
    int x = v;
    #pragma unroll
    for (int o = 1; o < 64; o <<= 1) {
        int y = __shfl_up(x, o);
        if ((t & 63) >= o) x += y;
    }
    __shared__ int wt[4];
    if ((t & 63) == 63) wt[t >> 6] = x;
    __syncthreads();
    int woff = bsums[blockIdx.x];
    for (int w = 0; w < (t >> 6); ++w) woff += wt[w];
    const int excl = woff + x - v;
    if (i < N_NODES) {
        row_ptr[i] = excl;
        cursor[i] = excl;
        if (i == N_NODES - 1) row_ptr[N_NODES] = excl + v;
    }
}

// Kernel P: place edges into CSR slots; precompute leaky logit e
__global__ __launch_bounds__(256) void kP(
    const int* __restrict__ src, const int* __restrict__ dst,
    const float* __restrict__ as_, const float* __restrict__ ad_,
    int* __restrict__ cursor, int2* __restrict__ csr)
{
    const int e = blockIdx.x * 256 + threadIdx.x;
    if (e >= N_EDGES) return;
    const int s = src[e], d = dst[e];
    const int slot = atomicAdd(cursor + d, 1);
    const float ev = lrelu(as_[s] + ad_[d]);
    csr[slot] = make_int2(s, __float_as_int(ev));
}

// Kernel G: wave per node -- max, softmax, weighted gather of xt rows,
// x = mem_enh + ctx + b_gat written in place over me_buf. Self-loop included.
__global__ __launch_bounds__(256) void kG(
    const int* __restrict__ row_ptr, const int2* __restrict__ csr,
    const float* __restrict__ as_, const float* __restrict__ ad_,
    const float* __restrict__ xt, const float* __restrict__ b_gat,
    float* __restrict__ me /* in: mem_enh, out: x */)
{
    const int wave = threadIdx.x >> 6, lane = threadIdx.x & 63;
    const float bg = b_gat[lane];
    for (int node = blockIdx.x * 4 + wave; node < N_NODES; node += gridDim.x * 4) {
        const int beg = row_ptr[node], end = row_ptr[node + 1];
        const float e_self = lrelu(as_[node] + ad_[node]);
        float m = e_self;
        for (int j = beg + lane; j < end; j += 64)
            m = fmaxf(m, __int_as_float(csr[j].y));
        #pragma unroll
        for (int o = 32; o; o >>= 1) m = fmaxf(m, __shfl_xor(m, o));
        float acc = 0.f, den = 0.f;
        for (int j = beg; j < end; ++j) {
            const int2 c = csr[j];
            const float w = __expf(__int_as_float(c.y) - m);
            den += w;
            acc += xt[(long)c.x * MEM + lane] * w;
        }
        const float wself = __expf(e_self - m);
        den += wself;
        acc += xt[(long)node * MEM + lane] * wself;
        const long off = (long)node * MEM + lane;
        me[off] = me[off] + acc / den + bg;
    }
}

// Kernel E v5: MFMA GRU. Wave wv owns out-cols [16wv,16wv+16) for all 6 gates.
// B-frags (bf16 weights) loaded once, live in VGPRs. Per 16-node tile: 12 MFMAs,
// lane-local GRU epilogue (D layout: col=lane&15, row=(lane>>4)*4+reg). No LDS.
__global__ __launch_bounds__(256) void kE(
    const float* __restrict__ x, const float* __restrict__ h,
    const float* __restrict__ w_ih, const float* __restrict__ w_hh,
    const float* __restrict__ b_ih, const float* __restrict__ b_hh,
    float* __restrict__ out)
{
    const int wv = threadIdx.x >> 6;      // col-block
    const int lane = threadIdx.x & 63;
    const int lr = lane & 15;             // A-row / B-col / D-col index
    const int lk = lane >> 4;             // k-block (inputs) / row-block (output)
    const int col = wv * 16 + lr;

    // B[k][c] = W[c][k]: lane holds W[col_g][8*lk + t + 32*hf], g = gate
    short8 Bf[6][2];
    #pragma unroll
    for (int g = 0; g < 6; ++g) {
        const float* W = (g < 3) ? w_ih : w_hh;
        const int row = (g % 3) * 64 + col;
        #pragma unroll
        for (int hf = 0; hf < 2; ++hf) {
            const float* p = W + (long)row * MEM + hf * 32 + lk * 8;
            short8 b;
            #pragma unroll
            for (int t = 0; t < 8; ++t) b[t] = bfr(p[t]);
            Bf[g][hf] = b;
        }
    }
    const float bias[6] = { b_ih[col], b_ih[64 + col], b_ih[128 + col],
                            b_hh[col], b_hh[64 + col], b_hh[128 + col] };

    for (int mt = blockIdx.x; mt < N_NODES / 16; mt += gridDim.x) {
        const int n0 = mt * 16;
        const float* rx = x + (long)(n0 + lr) * MEM + lk * 8;
        const float* rh = h + (long)(n0 + lr) * MEM + lk * 8;
        short8 Ax[2], Ah[2];
        #pragma unroll
        for (int hf = 0; hf < 2; ++hf) {
            short8 a, b;
            #pragma unroll
            for (int t = 0; t < 8; ++t) {
                a[t] = bfr(rx[hf * 32 + t]);
                b[t] = bfr(rh[hf * 32 + t]);
            }
            Ax[hf] = a; Ah[hf] = b;
        }
        f32x4 acc[6];
        #pragma unroll
        for (int g = 0; g < 6; ++g) {
            f32x4 z; z[0] = bias[g]; z[1] = bias[g]; z[2] = bias[g]; z[3] = bias[g];
            acc[g] = z;
        }
        #pragma unroll
        for (int g = 0; g < 3; ++g) {
            acc[g] = __builtin_amdgcn_mfma_f32_16x16x32_bf16(Ax[0], Bf[g][0], acc[g], 0, 0, 0);
            acc[g] = __builtin_amdgcn_mfma_f32_16x16x32_bf16(Ax[1], Bf[g][1], acc[g], 0, 0, 0);
        }
        #pragma unroll
        for (int g = 3; g < 6; ++g) {
            acc[g] = __builtin_amdgcn_mfma_f32_16x16x32_bf16(Ah[0], Bf[g][0], acc[g], 0, 0, 0);
            acc[g] = __builtin_amdgcn_mfma_f32_16x16x32_bf16(Ah[1], Bf[g][1], acc[g], 0, 0, 0);
        }
        // epilogue: lane holds nodes n0 + 4*lk + r (r=0..3), column `col`, all 6 gates
        #pragma unroll
        for (int r = 0; r < 4; ++r) {
            const int node = n0 + lk * 4 + r;
            const long off = (long)node * MEM + col;
            const float hv = h[off];
            const float rr = 1.f / (1.f + __expf(-(acc[0][r] + acc[3][r])));
            const float zz = 1.f / (1.f + __expf(-(acc[1][r] + acc[4][r])));
            const float nn = tanhf(acc[2][r] + rr * acc[5][r]);
            out[off] = (1.f - zz) * nn + zz * hv;
        }
    }
}

extern "C" void kernel_launch(void* const* d_in, const int* in_sizes, int n_in,
                              void* d_out, int out_size, void* d_ws, size_t ws_size,
                              hipStream_t stream) {
    const float* state = (const float*)d_in[0];
    const float* goal  = (const float*)d_in[1];
    const float* mem   = (const float*)d_in[2];
    const int*   ei    = (const int*)d_in[3];
    const float* w_in  = (const float*)d_in[4];
    const float* b_in  = (const float*)d_in[5];
    const float* w_gat = (const float*)d_in[6];
    const float* att_s = (const float*)d_in[7];
    const float* att_d = (const float*)d_in[8];
    const float* b_gat = (const float*)d_in[9];
    const float* w_ih  = (const float*)d_in[10];
    const float* w_hh  = (const float*)d_in[11];
    const float* b_ih  = (const float*)d_in[12];
    const float* b_hh  = (const float*)d_in[13];
    float* out = (float*)d_out;

    const int* e_src = ei;
    const int* e_dst = ei + N_EDGES;

    float* ws = (float*)d_ws;
    float* me_buf  = ws;                              // N*64 (becomes x after kG)
    float* xt_buf  = me_buf + (long)N_NODES * MEM;    // N*64
    float* as_buf  = xt_buf + (long)N_NODES * MEM;    // N
    float* ad_buf  = as_buf + N_NODES;                // N
    int*   deg     = (int*)(ad_buf + N_NODES);        // N
    int*   row_ptr = deg + N_NODES;                   // N+1
    int*   cursor  = row_ptr + N_NODES + 1;           // N
    int*   bsums   = cursor + N_NODES;                // NB
    long csr_off = (long)(bsums + NB - (int*)d_ws);
    csr_off = (csr_off + 1) & ~1L;                    // 8B align
    int2*  csr     = (int2*)((int*)d_ws + csr_off);   // E int2

    hipMemsetAsync(deg, 0, N_NODES * sizeof(int), stream);

    hipLaunchKernelGGL(kA, dim3(512), dim3(1024), 0, stream,
        state, goal, mem, w_in, b_in, w_gat, att_s, att_d,
        me_buf, xt_buf, as_buf, ad_buf);

    hipLaunchKernelGGL(kH, dim3((N_EDGES + 255) / 256), dim3(256), 0, stream, e_dst, deg);
    hipLaunchKernelGGL(kS1, dim3(NB), dim3(256), 0, stream, deg, bsums);
    hipLaunchKernelGGL(kS2, dim3(1), dim3(512), 0, stream, bsums);
    hipLaunchKernelGGL(kS3, dim3(NB), dim3(256), 0, stream, deg, bsums, row_ptr, cursor);
    hipLaunchKernelGGL(kP, dim3((N_EDGES + 255) / 256), dim3(256), 0, stream,
        e_src, e_dst, as_buf, ad_buf, cursor, csr);

    hipLaunchKernelGGL(kG, dim3(2048), dim3(256), 0, stream,
        row_ptr, csr, as_buf, ad_buf, xt_buf, b_gat, me_buf);

    hipLaunchKernelGGL(kE, dim3(1024), dim3(256), 0, stream,
        me_buf, mem, w_ih, w_hh, b_ih, b_hh, out);
}

// Round 8
// 474.456 us; speedup vs baseline: 5.2012x; 1.3014x over previous
//
#include <hip/hip_runtime.h>
#include <hip/hip_bf16.h>

#define N_NODES 100000
#define N_EDGES 1600000
#define NODE_DIM 128
#define MEM 64
#define NEG_SLOPE 0.2f
#define NB ((N_NODES + 255) / 256)  // 391 scan blocks

typedef __attribute__((ext_vector_type(8))) short short8;
typedef __attribute__((ext_vector_type(4))) float f32x4;

__device__ __forceinline__ float lrelu(float v) { return v >= 0.f ? v : NEG_SLOPE * v; }

// f32 -> bf16 (RNE) bit pattern
__device__ __forceinline__ unsigned short bfr(float f) {
    unsigned u = __float_as_uint(f);
    u = (u + 0x7FFFu + ((u >> 16) & 1u)) >> 16;
    return (unsigned short)u;
}
__device__ __forceinline__ float bf2f(unsigned short s) {
    return __uint_as_float(((unsigned)s) << 16);
}

// Kernel A (MFMA): per 16-node tile:
//   proj = state@w_in.T + b_in (4 MFMAs, K=128); me = proj+goal+mem -> global f32 + LDS bf16
//   xt   = me@w_gat.T          (2 MFMAs, K=64)  -> global bf16
//   a_s = xt@att_src, a_d = xt@att_dst via shfl col-reduce + LDS cross-wave combine
// 256 threads = 4 waves; wave wv owns out-cols [16wv,16wv+16).
__global__ __launch_bounds__(256) void kA(
    const float* __restrict__ state, const float* __restrict__ goal,
    const float* __restrict__ mem, const float* __restrict__ w_in,
    const float* __restrict__ b_in, const float* __restrict__ w_gat,
    const float* __restrict__ att_src, const float* __restrict__ att_dst,
    float* __restrict__ me_out, unsigned short* __restrict__ xt_out,
    float* __restrict__ as_out, float* __restrict__ ad_out)
{
    __shared__ unsigned short s_me[16][72];  // bf16 me tile; 144B row stride (16B aligned)
    __shared__ float s_red[4][16][2];        // per-wave (a_s,a_d) partials
    const int wv = threadIdx.x >> 6;
    const int lane = threadIdx.x & 63;
    const int lr = lane & 15;                // A-row / B-col / D-col
    const int lk = lane >> 4;                // k-block / D row-block
    const int col = wv * 16 + lr;

    // B-frags, loaded once: Bp[s][t] = w_in[col][s*32+lk*8+t]; Bx[s][t] = w_gat[col][s*32+lk*8+t]
    short8 Bp[4], Bx[2];
    #pragma unroll
    for (int s = 0; s < 4; ++s) {
        const float* p = w_in + (long)col * NODE_DIM + s * 32 + lk * 8;
        short8 b;
        #pragma unroll
        for (int t = 0; t < 8; ++t) b[t] = (short)bfr(p[t]);
        Bp[s] = b;
    }
    #pragma unroll
    for (int s = 0; s < 2; ++s) {
        const float* p = w_gat + (long)col * MEM + s * 32 + lk * 8;
        short8 b;
        #pragma unroll
        for (int t = 0; t < 8; ++t) b[t] = (short)bfr(p[t]);
        Bx[s] = b;
    }
    const float bcol = b_in[col];
    const float av_s = att_src[col], av_d = att_dst[col];

    for (int mt = blockIdx.x; mt < N_NODES / 16; mt += gridDim.x) {
        const int n0 = mt * 16;
        // A-frags from state (all 4 waves read same rows -> L1 hits)
        short8 Ap[4];
        #pragma unroll
        for (int s = 0; s < 4; ++s) {
            const float* p = state + (long)(n0 + lr) * NODE_DIM + s * 32 + lk * 8;
            short8 a;
            #pragma unroll
            for (int t = 0; t < 8; ++t) a[t] = (short)bfr(p[t]);
            Ap[s] = a;
        }
        f32x4 accp;
        accp[0] = bcol; accp[1] = bcol; accp[2] = bcol; accp[3] = bcol;
        #pragma unroll
        for (int s = 0; s < 4; ++s)
            accp = __builtin_amdgcn_mfma_f32_16x16x32_bf16(Ap[s], Bp[s], accp, 0, 0, 0);
        float mev[4];
        #pragma unroll
        for (int r = 0; r < 4; ++r) {
            const long off = (long)(n0 + lk * 4 + r) * MEM + col;
            mev[r] = accp[r] + goal[off] + mem[off];
            me_out[off] = mev[r];
        }
        __syncthreads();   // previous tile's s_me / s_red reads complete
        #pragma unroll
        for (int r = 0; r < 4; ++r) s_me[lk * 4 + r][col] = bfr(mev[r]);
        __syncthreads();   // s_me ready
        short8 Ax2[2];
        #pragma unroll
        for (int s = 0; s < 2; ++s)
            Ax2[s] = *(const short8*)&s_me[lr][s * 32 + lk * 8];
        f32x4 accx;
        accx[0] = 0.f; accx[1] = 0.f; accx[2] = 0.f; accx[3] = 0.f;
        #pragma unroll
        for (int s = 0; s < 2; ++s)
            accx = __builtin_amdgcn_mfma_f32_16x16x32_bf16(Ax2[s], Bx[s], accx, 0, 0, 0);
        float ps[4], pd[4];
        #pragma unroll
        for (int r = 0; r < 4; ++r) {
            const float xv = accx[r];
            xt_out[(long)(n0 + lk * 4 + r) * MEM + col] = bfr(xv);
            ps[r] = xv * av_s;
            pd[r] = xv * av_d;
        }
        #pragma unroll
        for (int r = 0; r < 4; ++r) {
            #pragma unroll
            for (int o = 1; o < 16; o <<= 1) {
                ps[r] += __shfl_xor(ps[r], o);
                pd[r] += __shfl_xor(pd[r], o);
            }
        }
        if (lr == 0) {
            #pragma unroll
            for (int r = 0; r < 4; ++r) {
                s_red[wv][lk * 4 + r][0] = ps[r];
                s_red[wv][lk * 4 + r][1] = pd[r];
            }
        }
        __syncthreads();   // s_red ready
        if (threadIdx.x < 32) {
            const int node = threadIdx.x >> 1, sel = threadIdx.x & 1;
            const float v = s_red[0][node][sel] + s_red[1][node][sel] +
                            s_red[2][node][sel] + s_red[3][node][sel];
            if (sel == 0) as_out[n0 + node] = v;
            else          ad_out[n0 + node] = v;
        }
    }
}

// Kernel H: in-degree histogram (int atomics)
__global__ __launch_bounds__(256) void kH(const int* __restrict__ dst, int* __restrict__ deg) {
    const int e = blockIdx.x * 256 + threadIdx.x;
    if (e < N_EDGES) atomicAdd(deg + dst[e], 1);
}

// Scan kernel 1: per-256-block sums of deg
__global__ __launch_bounds__(256) void kS1(const int* __restrict__ deg, int* __restrict__ bsums) {
    const int i = blockIdx.x * 256 + threadIdx.x;
    int s = (i < N_NODES) ? deg[i] : 0;
    #pragma unroll
    for (int o = 32; o; o >>= 1) s += __shfl_xor(s, o);
    __shared__ int ws_[4];
    if ((threadIdx.x & 63) == 0) ws_[threadIdx.x >> 6] = s;
    __syncthreads();
    if (threadIdx.x == 0) bsums[blockIdx.x] = ws_[0] + ws_[1] + ws_[2] + ws_[3];
}

// Scan kernel 2: exclusive scan of NB block sums (single block)
__global__ __launch_bounds__(512) void kS2(int* __restrict__ bsums) {
    const int t = threadIdx.x;
    int v = (t < NB) ? bsums[t] : 0;
    int x = v;
    #pragma unroll
    for (int o = 1; o < 64; o <<= 1) {
        int y = __shfl_up(x, o);
        if ((t & 63) >= o) x += y;
    }
    __shared__ int wt[8];
    if ((t & 63) == 63) wt[t >> 6] = x;
    __syncthreads();
    int woff = 0;
    for (int w = 0; w < (t >> 6); ++w) woff += wt[w];
    if (t < NB) bsums[t] = woff + x - v;  // exclusive
}

// Scan kernel 3: per-block exclusive scan + block offset -> row_ptr, cursor
__global__ __launch_bounds__(256) void kS3(const int* __restrict__ deg, const int* __restrict__ bsums,
                                           int* __restrict__ row_ptr, int* __restrict__ cursor) {
    const int i = blockIdx.x * 256 + threadIdx.x;
    const int t = threadIdx.x;
    int v = (i < N_NODES) ? deg[i] : 0;
    int x = v;
    #pragma unroll
    for (int o = 1; o < 64; o <<= 1) {
        int y = __shfl_up(x, o);
        if ((t & 63) >= o) x += y;
    }
    __shared__ int wt[4];
    if ((t & 63) == 63) wt[t >> 6] = x;
    __syncthreads();
    int woff = bsums[blockIdx.x];
    for (int w = 0; w < (t >> 6); ++w) woff += wt[w];
    const int excl = woff + x - v;
    if (i < N_NODES) {
        row_ptr[i] = excl;
        cursor[i] = excl;
        if (i == N_NODES - 1) row_ptr[N_NODES] = excl + v;
    }
}

// Kernel P: place edges into CSR slots; precompute leaky logit e
__global__ __launch_bounds__(256) void kP(
    const int* __restrict__ src, const int* __restrict__ dst,
    const float* __restrict__ as_, const float* __restrict__ ad_,
    int* __restrict__ cursor, int2* __restrict__ csr)
{
    const int e = blockIdx.x * 256 + threadIdx.x;
    if (e >= N_EDGES) return;
    const int s = src[e], d = dst[e];
    const int slot = atomicAdd(cursor + d, 1);
    const float ev = lrelu(as_[s] + ad_[d]);
    csr[slot] = make_int2(s, __float_as_int(ev));
}

// Kernel G: wave per node -- max, softmax, weighted gather of bf16 xt rows,
// x = mem_enh + ctx + b_gat written in place over me_buf. Self-loop included.
__global__ __launch_bounds__(256) void kG(
    const int* __restrict__ row_ptr, const int2* __restrict__ csr,
    const float* __restrict__ as_, const float* __restrict__ ad_,
    const unsigned short* __restrict__ xt, const float* __restrict__ b_gat,
    float* __restrict__ me /* in: mem_enh, out: x */)
{
    const int wave = threadIdx.x >> 6, lane = threadIdx.x & 63;
    const float bg = b_gat[lane];
    for (int node = blockIdx.x * 4 + wave; node < N_NODES; node += gridDim.x * 4) {
        const int beg = row_ptr[node], end = row_ptr[node + 1];
        const float e_self = lrelu(as_[node] + ad_[node]);
        float m = e_self;
        for (int j = beg + lane; j < end; j += 64)
            m = fmaxf(m, __int_as_float(csr[j].y));
        #pragma unroll
        for (int o = 32; o; o >>= 1) m = fmaxf(m, __shfl_xor(m, o));
        float acc = 0.f, den = 0.f;
        int j = beg;
        for (; j + 2 <= end; j += 2) {
            const int2 c0 = csr[j], c1 = csr[j + 1];
            const float x0 = bf2f(xt[(long)c0.x * MEM + lane]);
            const float x1 = bf2f(xt[(long)c1.x * MEM + lane]);
            const float w0 = __expf(__int_as_float(c0.y) - m);
            const float w1 = __expf(__int_as_float(c1.y) - m);
            den += w0 + w1;
            acc += x0 * w0 + x1 * w1;
        }
        if (j < end) {
            const int2 c = csr[j];
            const float w = __expf(__int_as_float(c.y) - m);
            den += w;
            acc += bf2f(xt[(long)c.x * MEM + lane]) * w;
        }
        const float wself = __expf(e_self - m);
        den += wself;
        acc += bf2f(xt[(long)node * MEM + lane]) * wself;
        const long off = (long)node * MEM + lane;
        me[off] = me[off] + acc / den + bg;
    }
}

// Kernel E: MFMA GRU. Wave wv owns out-cols [16wv,16wv+16) for all 6 gates.
__global__ __launch_bounds__(256) void kE(
    const float* __restrict__ x, const float* __restrict__ h,
    const float* __restrict__ w_ih, const float* __restrict__ w_hh,
    const float* __restrict__ b_ih, const float* __restrict__ b_hh,
    float* __restrict__ out)
{
    const int wv = threadIdx.x >> 6;
    const int lane = threadIdx.x & 63;
    const int lr = lane & 15;
    const int lk = lane >> 4;
    const int col = wv * 16 + lr;

    short8 Bf[6][2];
    #pragma unroll
    for (int g = 0; g < 6; ++g) {
        const float* W = (g < 3) ? w_ih : w_hh;
        const int row = (g % 3) * 64 + col;
        #pragma unroll
        for (int hf = 0; hf < 2; ++hf) {
            const float* p = W + (long)row * MEM + hf * 32 + lk * 8;
            short8 b;
            #pragma unroll
            for (int t = 0; t < 8; ++t) b[t] = (short)bfr(p[t]);
            Bf[g][hf] = b;
        }
    }
    const float bias[6] = { b_ih[col], b_ih[64 + col], b_ih[128 + col],
                            b_hh[col], b_hh[64 + col], b_hh[128 + col] };

    for (int mt = blockIdx.x; mt < N_NODES / 16; mt += gridDim.x) {
        const int n0 = mt * 16;
        const float* rx = x + (long)(n0 + lr) * MEM + lk * 8;
        const float* rh = h + (long)(n0 + lr) * MEM + lk * 8;
        short8 Ax[2], Ah[2];
        #pragma unroll
        for (int hf = 0; hf < 2; ++hf) {
            short8 a, b;
            #pragma unroll
            for (int t = 0; t < 8; ++t) {
                a[t] = (short)bfr(rx[hf * 32 + t]);
                b[t] = (short)bfr(rh[hf * 32 + t]);
            }
            Ax[hf] = a; Ah[hf] = b;
        }
        f32x4 acc[6];
        #pragma unroll
        for (int g = 0; g < 6; ++g) {
            f32x4 z; z[0] = bias[g]; z[1] = bias[g]; z[2] = bias[g]; z[3] = bias[g];
            acc[g] = z;
        }
        #pragma unroll
        for (int g = 0; g < 3; ++g) {
            acc[g] = __builtin_amdgcn_mfma_f32_16x16x32_bf16(Ax[0], Bf[g][0], acc[g], 0, 0, 0);
            acc[g] = __builtin_amdgcn_mfma_f32_16x16x32_bf16(Ax[1], Bf[g][1], acc[g], 0, 0, 0);
        }
        #pragma unroll
        for (int g = 3; g < 6; ++g) {
            acc[g] = __builtin_amdgcn_mfma_f32_16x16x32_bf16(Ah[0], Bf[g][0], acc[g], 0, 0, 0);
            acc[g] = __builtin_amdgcn_mfma_f32_16x16x32_bf16(Ah[1], Bf[g][1], acc[g], 0, 0, 0);
        }
        #pragma unroll
        for (int r = 0; r < 4; ++r) {
            const int node = n0 + lk * 4 + r;
            const long off = (long)node * MEM + col;
            const float hv = h[off];
            const float rr = 1.f / (1.f + __expf(-(acc[0][r] + acc[3][r])));
            const float zz = 1.f / (1.f + __expf(-(acc[1][r] + acc[4][r])));
            const float nn = tanhf(acc[2][r] + rr * acc[5][r]);
            out[off] = (1.f - zz) * nn + zz * hv;
        }
    }
}

extern "C" void kernel_launch(void* const* d_in, const int* in_sizes, int n_in,
                              void* d_out, int out_size, void* d_ws, size_t ws_size,
                              hipStream_t stream) {
    const float* state = (const float*)d_in[0];
    const float* goal  = (const float*)d_in[1];
    const float* mem   = (const float*)d_in[2];
    const int*   ei    = (const int*)d_in[3];
    const float* w_in  = (const float*)d_in[4];
    const float* b_in  = (const float*)d_in[5];
    const float* w_gat = (const float*)d_in[6];
    const float* att_s = (const float*)d_in[7];
    const float* att_d = (const float*)d_in[8];
    const float* b_gat = (const float*)d_in[9];
    const float* w_ih  = (const float*)d_in[10];
    const float* w_hh  = (const float*)d_in[11];
    const float* b_ih  = (const float*)d_in[12];
    const float* b_hh  = (const float*)d_in[13];
    float* out = (float*)d_out;

    const int* e_src = ei;
    const int* e_dst = ei + N_EDGES;

    // workspace layout (4-byte granularity)
    float* ws = (float*)d_ws;
    float* me_buf  = ws;                                   // N*64 f32 (becomes x after kG)
    unsigned short* xt_bf = (unsigned short*)(me_buf + (long)N_NODES * MEM); // N*64 bf16
    float* as_buf  = (float*)(xt_bf + (long)N_NODES * MEM);// N
    float* ad_buf  = as_buf + N_NODES;                     // N
    int*   deg     = (int*)(ad_buf + N_NODES);             // N
    int*   row_ptr = deg + N_NODES;                        // N+1
    int*   cursor  = row_ptr + N_NODES + 1;                // N
    int*   bsums   = cursor + N_NODES;                     // NB
    long csr_off = (long)(bsums + NB - (int*)d_ws);
    csr_off = (csr_off + 1) & ~1L;                         // 8B align
    int2*  csr     = (int2*)((int*)d_ws + csr_off);        // E int2

    hipMemsetAsync(deg, 0, N_NODES * sizeof(int), stream);

    hipLaunchKernelGGL(kA, dim3(1024), dim3(256), 0, stream,
        state, goal, mem, w_in, b_in, w_gat, att_s, att_d,
        me_buf, xt_bf, as_buf, ad_buf);

    hipLaunchKernelGGL(kH, dim3((N_EDGES + 255) / 256), dim3(256), 0, stream, e_dst, deg);
    hipLaunchKernelGGL(kS1, dim3(NB), dim3(256), 0, stream, deg, bsums);
    hipLaunchKernelGGL(kS2, dim3(1), dim3(512), 0, stream, bsums);
    hipLaunchKernelGGL(kS3, dim3(NB), dim3(256), 0, stream, deg, bsums, row_ptr, cursor);
    hipLaunchKernelGGL(kP, dim3((N_EDGES + 255) / 256), dim3(256), 0, stream,
        e_src, e_dst, as_buf, ad_buf, cursor, csr);

    hipLaunchKernelGGL(kG, dim3(2048), dim3(256), 0, stream,
        row_ptr, csr, as_buf, ad_buf, xt_bf, b_gat, me_buf);

    hipLaunchKernelGGL(kE, dim3(1024), dim3(256), 0, stream,
        me_buf, mem, w_ih, w_hh, b_ih, b_hh, out);
}

// Round 9
// 435.379 us; speedup vs baseline: 5.6680x; 1.0898x over previous
//
#include <hip/hip_runtime.h>
#include <hip/hip_bf16.h>

#define N_NODES 100000
#define N_EDGES 1600000
#define NODE_DIM 128
#define MEM 64
#define NEG_SLOPE 0.2f
#define NB ((N_NODES + 255) / 256)  // 391 scan blocks

typedef __attribute__((ext_vector_type(8))) short short8;
typedef __attribute__((ext_vector_type(4))) float f32x4;

__device__ __forceinline__ float lrelu(float v) { return v >= 0.f ? v : NEG_SLOPE * v; }

// f32 -> bf16 (RNE) bit pattern
__device__ __forceinline__ unsigned short bfr(float f) {
    unsigned u = __float_as_uint(f);
    u = (u + 0x7FFFu + ((u >> 16) & 1u)) >> 16;
    return (unsigned short)u;
}
__device__ __forceinline__ float bf2f(unsigned short s) {
    return __uint_as_float(((unsigned)s) << 16);
}

// Kernel A (MFMA): per 16-node tile:
//   proj = state@w_in.T + b_in (4 MFMAs, K=128); me = proj+goal+mem -> global bf16 + LDS bf16
//   xt   = me@w_gat.T          (2 MFMAs, K=64)  -> global bf16
//   a_s/a_d via shfl col-reduce + LDS cross-wave combine
__global__ __launch_bounds__(256) void kA(
    const float* __restrict__ state, const float* __restrict__ goal,
    const float* __restrict__ mem, const float* __restrict__ w_in,
    const float* __restrict__ b_in, const float* __restrict__ w_gat,
    const float* __restrict__ att_src, const float* __restrict__ att_dst,
    unsigned short* __restrict__ me_out, unsigned short* __restrict__ xt_out,
    float* __restrict__ as_out, float* __restrict__ ad_out)
{
    __shared__ unsigned short s_me[16][72];  // bf16 me tile; 144B row stride (16B aligned)
    __shared__ float s_red[4][16][2];        // per-wave (a_s,a_d) partials
    const int wv = threadIdx.x >> 6;
    const int lane = threadIdx.x & 63;
    const int lr = lane & 15;                // A-row / B-col / D-col
    const int lk = lane >> 4;                // k-block / D row-block
    const int col = wv * 16 + lr;

    short8 Bp[4], Bx[2];
    #pragma unroll
    for (int s = 0; s < 4; ++s) {
        const float* p = w_in + (long)col * NODE_DIM + s * 32 + lk * 8;
        short8 b;
        #pragma unroll
        for (int t = 0; t < 8; ++t) b[t] = (short)bfr(p[t]);
        Bp[s] = b;
    }
    #pragma unroll
    for (int s = 0; s < 2; ++s) {
        const float* p = w_gat + (long)col * MEM + s * 32 + lk * 8;
        short8 b;
        #pragma unroll
        for (int t = 0; t < 8; ++t) b[t] = (short)bfr(p[t]);
        Bx[s] = b;
    }
    const float bcol = b_in[col];
    const float av_s = att_src[col], av_d = att_dst[col];

    for (int mt = blockIdx.x; mt < N_NODES / 16; mt += gridDim.x) {
        const int n0 = mt * 16;
        short8 Ap[4];
        #pragma unroll
        for (int s = 0; s < 4; ++s) {
            const float* p = state + (long)(n0 + lr) * NODE_DIM + s * 32 + lk * 8;
            short8 a;
            #pragma unroll
            for (int t = 0; t < 8; ++t) a[t] = (short)bfr(p[t]);
            Ap[s] = a;
        }
        f32x4 accp;
        accp[0] = bcol; accp[1] = bcol; accp[2] = bcol; accp[3] = bcol;
        #pragma unroll
        for (int s = 0; s < 4; ++s)
            accp = __builtin_amdgcn_mfma_f32_16x16x32_bf16(Ap[s], Bp[s], accp, 0, 0, 0);
        unsigned short mev[4];
        #pragma unroll
        for (int r = 0; r < 4; ++r) {
            const long off = (long)(n0 + lk * 4 + r) * MEM + col;
            const float v = accp[r] + goal[off] + mem[off];
            mev[r] = bfr(v);
            me_out[off] = mev[r];
        }
        __syncthreads();   // previous tile's s_me / s_red reads complete
        #pragma unroll
        for (int r = 0; r < 4; ++r) s_me[lk * 4 + r][col] = mev[r];
        __syncthreads();   // s_me ready
        short8 Ax2[2];
        #pragma unroll
        for (int s = 0; s < 2; ++s)
            Ax2[s] = *(const short8*)&s_me[lr][s * 32 + lk * 8];
        f32x4 accx;
        accx[0] = 0.f; accx[1] = 0.f; accx[2] = 0.f; accx[3] = 0.f;
        #pragma unroll
        for (int s = 0; s < 2; ++s)
            accx = __builtin_amdgcn_mfma_f32_16x16x32_bf16(Ax2[s], Bx[s], accx, 0, 0, 0);
        float ps[4], pd[4];
        #pragma unroll
        for (int r = 0; r < 4; ++r) {
            const float xv = accx[r];
            xt_out[(long)(n0 + lk * 4 + r) * MEM + col] = bfr(xv);
            ps[r] = xv * av_s;
            pd[r] = xv * av_d;
        }
        #pragma unroll
        for (int r = 0; r < 4; ++r) {
            #pragma unroll
            for (int o = 1; o < 16; o <<= 1) {
                ps[r] += __shfl_xor(ps[r], o);
                pd[r] += __shfl_xor(pd[r], o);
            }
        }
        if (lr == 0) {
            #pragma unroll
            for (int r = 0; r < 4; ++r) {
                s_red[wv][lk * 4 + r][0] = ps[r];
                s_red[wv][lk * 4 + r][1] = pd[r];
            }
        }
        __syncthreads();   // s_red ready
        if (threadIdx.x < 32) {
            const int node = threadIdx.x >> 1, sel = threadIdx.x & 1;
            const float v = s_red[0][node][sel] + s_red[1][node][sel] +
                            s_red[2][node][sel] + s_red[3][node][sel];
            if (sel == 0) as_out[n0 + node] = v;
            else          ad_out[n0 + node] = v;
        }
    }
}

// Kernel H: in-degree histogram (int atomics)
__global__ __launch_bounds__(256) void kH(const int* __restrict__ dst, int* __restrict__ deg) {
    const int e = blockIdx.x * 256 + threadIdx.x;
    if (e < N_EDGES) atomicAdd(deg + dst[e], 1);
}

// Scan kernel 1: per-256-block sums of deg
__global__ __launch_bounds__(256) void kS1(const int* __restrict__ deg, int* __restrict__ bsums) {
    const int i = blockIdx.x * 256 + threadIdx.x;
    int s = (i < N_NODES) ? deg[i] : 0;
    #pragma unroll
    for (int o = 32; o; o >>= 1) s += __shfl_xor(s, o);
    __shared__ int ws_[4];
    if ((threadIdx.x & 63) == 0) ws_[threadIdx.x >> 6] = s;
    __syncthreads();
    if (threadIdx.x == 0) bsums[blockIdx.x] = ws_[0] + ws_[1] + ws_[2] + ws_[3];
}

// Scan kernel 2: exclusive scan of NB block sums (single block)
__global__ __launch_bounds__(512) void kS2(int* __restrict__ bsums) {
    const int t = threadIdx.x;
    int v = (t < NB) ? bsums[t] : 0;
    int x = v;
    #pragma unroll
    for (int o = 1; o < 64; o <<= 1) {
        int y = __shfl_up(x, o);
        if ((t & 63) >= o) x += y;
    }
    __shared__ int wt[8];
    if ((t & 63) == 63) wt[t >> 6] = x;
    __syncthreads();
    int woff = 0;
    for (int w = 0; w < (t >> 6); ++w) woff += wt[w];
    if (t < NB) bsums[t] = woff + x - v;  // exclusive
}

// Scan kernel 3: per-block exclusive scan + block offset -> row_ptr, cursor
__global__ __launch_bounds__(256) void kS3(const int* __restrict__ deg, const int* __restrict__ bsums,
                                           int* __restrict__ row_ptr, int* __restrict__ cursor) {
    const int i = blockIdx.x * 256 + threadIdx.x;
    const int t = threadIdx.x;
    int v = (i < N_NODES) ? deg[i] : 0;
    int x = v;
    #pragma unroll
    for (int o = 1; o < 64; o <<= 1) {
        int y = __shfl_up(x, o);
        if ((t & 63) >= o) x += y;
    }
    __shared__ int wt[4];
    if ((t & 63) == 63) wt[t >> 6] = x;
    __syncthreads();
    int woff = bsums[blockIdx.x];
    for (int w = 0; w < (t >> 6); ++w) woff += wt[w];
    const int excl = woff + x - v;
    if (i < N_NODES) {
        row_ptr[i] = excl;
        cursor[i] = excl;
        if (i == N_NODES - 1) row_ptr[N_NODES] = excl + v;
    }
}

// Kernel P: place edges into CSR slots; precompute leaky logit e
__global__ __launch_bounds__(256) void kP(
    const int* __restrict__ src, const int* __restrict__ dst,
    const float* __restrict__ as_, const float* __restrict__ ad_,
    int* __restrict__ cursor, int2* __restrict__ csr)
{
    const int e = blockIdx.x * 256 + threadIdx.x;
    if (e >= N_EDGES) return;
    const int s = src[e], d = dst[e];
    const int slot = atomicAdd(cursor + d, 1);
    const float ev = lrelu(as_[s] + ad_[d]);
    csr[slot] = make_int2(s, __float_as_int(ev));
}

// Kernel G v3: wave per node. Half-wave edge split: lanes[0,32) even-parity edges,
// lanes[32,64) odd-parity; each lane loads a uint (2 bf16 cols) per edge -> 4B gathers,
// 4 gathers in flight (2-unroll). Cross-parity combine via shfl_xor(32).
// me (bf16) RMW in place: x = me + ctx + b_gat. Self-loop included.
__global__ __launch_bounds__(256) void kG(
    const int* __restrict__ row_ptr, const int2* __restrict__ csr,
    const float* __restrict__ as_, const float* __restrict__ ad_,
    const unsigned short* __restrict__ xt, const float* __restrict__ b_gat,
    unsigned short* __restrict__ me /* bf16, in: mem_enh, out: x */)
{
    const int wave = threadIdx.x >> 6, lane = threadIdx.x & 63;
    const int eo = lane >> 5, c2 = lane & 31;
    const float bg0 = b_gat[2 * c2], bg1 = b_gat[2 * c2 + 1];
    const int* csr_y = (const int*)csr;  // logit at index 2*j+1
    for (int node = blockIdx.x * 4 + wave; node < N_NODES; node += gridDim.x * 4) {
        const int beg = row_ptr[node], end = row_ptr[node + 1];
        const float e_self = lrelu(as_[node] + ad_[node]);
        // phase 1: max (all 64 lanes, 4B logit loads)
        float m = e_self;
        for (int j = beg + lane; j < end; j += 64)
            m = fmaxf(m, __int_as_float(csr_y[2 * j + 1]));
        #pragma unroll
        for (int o = 32; o; o >>= 1) m = fmaxf(m, __shfl_xor(m, o));
        // phase 2: parity-split accumulate, 2 edges per iter in flight per half
        float acc0 = 0.f, acc1 = 0.f, den = 0.f;
        int j = beg + eo;
        for (; j + 2 < end; j += 4) {
            const int2 ca = csr[j], cb = csr[j + 2];
            const unsigned ua = *(const unsigned*)&xt[((unsigned)ca.x << 6) + 2 * c2];
            const unsigned ub = *(const unsigned*)&xt[((unsigned)cb.x << 6) + 2 * c2];
            const float wa = __expf(__int_as_float(ca.y) - m);
            const float wb = __expf(__int_as_float(cb.y) - m);
            den += wa + wb;
            acc0 += bf2f((unsigned short)(ua & 0xFFFF)) * wa + bf2f((unsigned short)(ub & 0xFFFF)) * wb;
            acc1 += bf2f((unsigned short)(ua >> 16)) * wa + bf2f((unsigned short)(ub >> 16)) * wb;
        }
        if (j < end) {
            const int2 c = csr[j];
            const unsigned u = *(const unsigned*)&xt[((unsigned)c.x << 6) + 2 * c2];
            const float w = __expf(__int_as_float(c.y) - m);
            den += w;
            acc0 += bf2f((unsigned short)(u & 0xFFFF)) * w;
            acc1 += bf2f((unsigned short)(u >> 16)) * w;
        }
        // combine parities
        acc0 += __shfl_xor(acc0, 32);
        acc1 += __shfl_xor(acc1, 32);
        den  += __shfl_xor(den, 32);
        // self loop
        const float wself = __expf(e_self - m);
        den += wself;
        const unsigned us = *(const unsigned*)&xt[((unsigned)node << 6) + 2 * c2];
        acc0 += bf2f((unsigned short)(us & 0xFFFF)) * wself;
        acc1 += bf2f((unsigned short)(us >> 16)) * wself;
        if (eo == 0) {
            const float inv = 1.f / den;
            unsigned short* mp = me + ((long)node << 6) + 2 * c2;
            const unsigned um = *(const unsigned*)mp;
            const float r0 = bf2f((unsigned short)(um & 0xFFFF)) + acc0 * inv + bg0;
            const float r1 = bf2f((unsigned short)(um >> 16)) + acc1 * inv + bg1;
            *(unsigned*)mp = (unsigned)bfr(r0) | ((unsigned)bfr(r1) << 16);
        }
    }
}

// Kernel E: MFMA GRU. x is bf16 (direct short8 loads); h stays f32.
__global__ __launch_bounds__(256) void kE(
    const unsigned short* __restrict__ x, const float* __restrict__ h,
    const float* __restrict__ w_ih, const float* __restrict__ w_hh,
    const float* __restrict__ b_ih, const float* __restrict__ b_hh,
    float* __restrict__ out)
{
    const int wv = threadIdx.x >> 6;
    const int lane = threadIdx.x & 63;
    const int lr = lane & 15;
    const int lk = lane >> 4;
    const int col = wv * 16 + lr;

    short8 Bf[6][2];
    #pragma unroll
    for (int g = 0; g < 6; ++g) {
        const float* W = (g < 3) ? w_ih : w_hh;
        const int row = (g % 3) * 64 + col;
        #pragma unroll
        for (int hf = 0; hf < 2; ++hf) {
            const float* p = W + (long)row * MEM + hf * 32 + lk * 8;
            short8 b;
            #pragma unroll
            for (int t = 0; t < 8; ++t) b[t] = (short)bfr(p[t]);
            Bf[g][hf] = b;
        }
    }
    const float bias[6] = { b_ih[col], b_ih[64 + col], b_ih[128 + col],
                            b_hh[col], b_hh[64 + col], b_hh[128 + col] };

    for (int mt = blockIdx.x; mt < N_NODES / 16; mt += gridDim.x) {
        const int n0 = mt * 16;
        const float* rh = h + (long)(n0 + lr) * MEM + lk * 8;
        short8 Ax[2], Ah[2];
        #pragma unroll
        for (int hf = 0; hf < 2; ++hf) {
            Ax[hf] = *(const short8*)(x + (long)(n0 + lr) * MEM + hf * 32 + lk * 8);
            short8 b;
            #pragma unroll
            for (int t = 0; t < 8; ++t) b[t] = (short)bfr(rh[hf * 32 + t]);
            Ah[hf] = b;
        }
        f32x4 acc[6];
        #pragma unroll
        for (int g = 0; g < 6; ++g) {
            f32x4 z; z[0] = bias[g]; z[1] = bias[g]; z[2] = bias[g]; z[3] = bias[g];
            acc[g] = z;
        }
        #pragma unroll
        for (int g = 0; g < 3; ++g) {
            acc[g] = __builtin_amdgcn_mfma_f32_16x16x32_bf16(Ax[0], Bf[g][0], acc[g], 0, 0, 0);
            acc[g] = __builtin_amdgcn_mfma_f32_16x16x32_bf16(Ax[1], Bf[g][1], acc[g], 0, 0, 0);
        }
        #pragma unroll
        for (int g = 3; g < 6; ++g) {
            acc[g] = __builtin_amdgcn_mfma_f32_16x16x32_bf16(Ah[0], Bf[g][0], acc[g], 0, 0, 0);
            acc[g] = __builtin_amdgcn_mfma_f32_16x16x32_bf16(Ah[1], Bf[g][1], acc[g], 0, 0, 0);
        }
        #pragma unroll
        for (int r = 0; r < 4; ++r) {
            const int node = n0 + lk * 4 + r;
            const long off = (long)node * MEM + col;
            const float hv = h[off];
            const float rr = 1.f / (1.f + __expf(-(acc[0][r] + acc[3][r])));
            const float zz = 1.f / (1.f + __expf(-(acc[1][r] + acc[4][r])));
            const float nn = tanhf(acc[2][r] + rr * acc[5][r]);
            out[off] = (1.f - zz) * nn + zz * hv;
        }
    }
}

extern "C" void kernel_launch(void* const* d_in, const int* in_sizes, int n_in,
                              void* d_out, int out_size, void* d_ws, size_t ws_size,
                              hipStream_t stream) {
    const float* state = (const float*)d_in[0];
    const float* goal  = (const float*)d_in[1];
    const float* mem   = (const float*)d_in[2];
    const int*   ei    = (const int*)d_in[3];
    const float* w_in  = (const float*)d_in[4];
    const float* b_in  = (const float*)d_in[5];
    const float* w_gat = (const float*)d_in[6];
    const float* att_s = (const float*)d_in[7];
    const float* att_d = (const float*)d_in[8];
    const float* b_gat = (const float*)d_in[9];
    const float* w_ih  = (const float*)d_in[10];
    const float* w_hh  = (const float*)d_in[11];
    const float* b_ih  = (const float*)d_in[12];
    const float* b_hh  = (const float*)d_in[13];
    float* out = (float*)d_out;

    const int* e_src = ei;
    const int* e_dst = ei + N_EDGES;

    // workspace layout
    unsigned short* me16 = (unsigned short*)d_ws;               // N*64 bf16 (becomes x)
    unsigned short* xt_bf = me16 + (long)N_NODES * MEM;         // N*64 bf16
    float* as_buf  = (float*)(xt_bf + (long)N_NODES * MEM);     // N
    float* ad_buf  = as_buf + N_NODES;                          // N
    int*   deg     = (int*)(ad_buf + N_NODES);                  // N
    int*   row_ptr = deg + N_NODES;                             // N+1
    int*   cursor  = row_ptr + N_NODES + 1;                     // N
    int*   bsums   = cursor + N_NODES;                          // NB
    long csr_off = (long)(bsums + NB - (int*)d_ws);
    csr_off = (csr_off + 1) & ~1L;                              // 8B align
    int2*  csr     = (int2*)((int*)d_ws + csr_off);             // E int2

    hipMemsetAsync(deg, 0, N_NODES * sizeof(int), stream);

    hipLaunchKernelGGL(kA, dim3(1024), dim3(256), 0, stream,
        state, goal, mem, w_in, b_in, w_gat, att_s, att_d,
        me16, xt_bf, as_buf, ad_buf);

    hipLaunchKernelGGL(kH, dim3((N_EDGES + 255) / 256), dim3(256), 0, stream, e_dst, deg);
    hipLaunchKernelGGL(kS1, dim3(NB), dim3(256), 0, stream, deg, bsums);
    hipLaunchKernelGGL(kS2, dim3(1), dim3(512), 0, stream, bsums);
    hipLaunchKernelGGL(kS3, dim3(NB), dim3(256), 0, stream, deg, bsums, row_ptr, cursor);
    hipLaunchKernelGGL(kP, dim3((N_EDGES + 255) / 256), dim3(256), 0, stream,
        e_src, e_dst, as_buf, ad_buf, cursor, csr);

    hipLaunchKernelGGL(kG, dim3(2048), dim3(256), 0, stream,
        row_ptr, csr, as_buf, ad_buf, xt_bf, b_gat, me16);

    hipLaunchKernelGGL(kE, dim3(1024), dim3(256), 0, stream,
        me16, mem, w_ih, w_hh, b_ih, b_hh, out);
}